// Round 16
// baseline (209.864 us; speedup 1.0000x reference)
//
#include <hip/hip_runtime.h>
#include <hip/hip_fp16.h>

#define NN 50000     // nodes
#define NE 800000    // edges
#define NG 1024      // graphs
#define NP 16384     // pairs
#define NCL 16       // cell lines
#define INCH 64
#define EMB 128
#define HID 256

#define NB 391       // node buckets of 128 (CDIV(NN,128))
#define NCHUNK 400   // edge chunks
#define EPB 2000     // edges per chunk (NE = 400*2000 exactly)

#define CDIV(a,b) (((a)+(b)-1)/(b))

typedef _Float16 f16x8 __attribute__((ext_vector_type(8)));
typedef float    f32x4 __attribute__((ext_vector_type(4)));
typedef unsigned short ushort_t;

// ---------------- block exclusive scan (NW waves) ----------------
template<int NW>
__device__ __forceinline__ int block_excl_scan(int v, int t, int* incl_out) {
    int lane = t & 63, w = t >> 6;
    int s = v;
#pragma unroll
    for (int d = 1; d < 64; d <<= 1) {
        int u = __shfl_up(s, d, 64);
        if (lane >= d) s += u;
    }
    __shared__ int wsum[NW];
    if (lane == 63) wsum[w] = s;
    __syncthreads();
    int add = 0;
    for (int k = 0; k < w; ++k) add += wsum[k];
    *incl_out = s + add;
    return s + add - v;
}

// ---------------- fused prep+cnt ----------------
// blocks [0,400): edge-chunk histogram; [400,912): Whl hi/lo; [912,944): w1t;
// [944,1008): w2t; [1008,1012): inv counts.
__global__ __launch_bounds__(256) void k_prep0(const int* __restrict__ cols,
                                               const float* __restrict__ c1w,
                                               const float* __restrict__ c2w,
                                               const float* __restrict__ rw1,
                                               const int* __restrict__ batch,
                                               int* __restrict__ cnt,
                                               __half* __restrict__ w1t,
                                               __half* __restrict__ w2t,
                                               __half* __restrict__ Whl,
                                               float* __restrict__ inv) {
    __shared__ int hist[NB];
    int bid = blockIdx.x, t = threadIdx.x;
    if (bid < 400) {
        int ch = bid;
        for (int b = t; b < NB; b += 256) hist[b] = 0;
        __syncthreads();
        for (int e = ch * EPB + t; e < (ch + 1) * EPB; e += 256)
            atomicAdd(&hist[cols[e] >> 7], 1);
        __syncthreads();
        for (int b = t; b < NB; b += 256) cnt[b * NCHUNK + ch] = hist[b];
    } else if (bid < 912) {
        int i = (bid - 400) * 256 + t;            // 0..131071 chunk-units
        int ch = i & 15, tg = (i >> 4) & 255, z = i >> 12;
        int c = z >> 1, part = z & 1;
        f16x8 hi, lo;
#pragma unroll
        for (int j = 0; j < 8; ++j) {
            float v = rw1[(size_t)c * 65536 + (size_t)(part * 128 + ch * 8 + j) * 256 + tg];
            _Float16 h = (_Float16)v;
            hi[j] = h;
            lo[j] = (_Float16)(v - (float)h);
        }
        size_t base = ((size_t)z * 256 + tg) * 16 + ch;
        ((f16x8*)Whl)[base] = hi;
        ((f16x8*)Whl)[(size_t)32 * 256 * 16 + base] = lo;
    } else if (bid < 944) {
        int i = (bid - 912) * 256 + t;            // 0..8191
        int k = i >> 7, n = i & 127;
        w1t[n * INCH + k] = __float2half(c1w[i]);
    } else if (bid < 1008) {
        int i = (bid - 944) * 256 + t;            // 0..16383
        int k = i >> 7, n = i & 127;
        w2t[n * EMB + k] = __float2half(c2w[i]);
    } else {
        int g = (bid - 1008) * 256 + t;           // 0..1023
        int lo_ = 0, hi_ = NN;
        while (lo_ < hi_) { int m = (lo_ + hi_) >> 1; if (batch[m] < g) lo_ = m + 1; else hi_ = m; }
        int s = lo_;
        lo_ = 0; hi_ = NN;
        while (lo_ < hi_) { int m = (lo_ + hi_) >> 1; if (batch[m] < g + 1) lo_ = m + 1; else hi_ = m; }
        float c = (float)(lo_ - s);
        inv[g] = 1.f / fmaxf(c, 1.f);
    }
}

// ---------------- Pass B: per-bucket scan over chunks -> cnt excl, btot ----------------
__global__ __launch_bounds__(512) void k_bscan(int* __restrict__ cnt,
                                               int* __restrict__ btot) {
    int b = blockIdx.x, t = threadIdx.x;
    int v = (t < NCHUNK) ? cnt[b * NCHUNK + t] : 0;
    int incl;
    int excl = block_excl_scan<8>(v, t, &incl);
    if (t < NCHUNK) cnt[b * NCHUNK + t] = excl;
    if (t == NCHUNK - 1) btot[b] = incl;
}

// ---------------- Pass C: partition edges; bbase computed in-block ----------------
__global__ __launch_bounds__(256) void k_part(const int* __restrict__ rows,
                                              const int* __restrict__ cols,
                                              const int* __restrict__ cnt,
                                              const int* __restrict__ btot,
                                              int* __restrict__ bbase_out,
                                              int* __restrict__ ebuf) {
    __shared__ int bb[NB + 1];
    __shared__ int cur[NB];
    __shared__ int S0s;
    int ch = blockIdx.x, t = threadIdx.x;
    int incl;
    int v0 = btot[t];
    int e0 = block_excl_scan<4>(v0, t, &incl);
    bb[t] = e0;
    if (t == 255) S0s = incl;
    __syncthreads();
    int t2 = t + 256;
    int v1 = (t2 < NB) ? btot[t2] : 0;
    int e1 = block_excl_scan<4>(v1, t, &incl);
    if (t2 <= NB) bb[t2] = e1 + S0s;
    __syncthreads();
    for (int b = t; b < NB; b += 256) cur[b] = bb[b] + cnt[b * NCHUNK + ch];
    if (ch == 0)
        for (int i = t; i <= NB; i += 256) bbase_out[i] = bb[i];
    __syncthreads();
    for (int e = ch * EPB + t; e < (ch + 1) * EPB; e += 256) {
        int c = cols[e], r = rows[e];
        int pos = atomicAdd(&cur[c >> 7], 1);
        ebuf[pos] = (r << 7) | (c & 127);
    }
}

// ---------------- Pass D: bucket counting sort -> srows(ushort)/off/dinv + x->fp16 ----------------
__global__ __launch_bounds__(256) void k_bsort(const int* __restrict__ ebuf,
                                               const int* __restrict__ bbase,
                                               const float* __restrict__ x,
                                               int* __restrict__ off,
                                               float* __restrict__ dinv,
                                               ushort_t* __restrict__ srows,
                                               __half* __restrict__ xs) {
    __shared__ int   ldeg[128];
    __shared__ int   lcur[128];
    __shared__ float ldinv[128];
    int b = blockIdx.x, t = threadIdx.x;
    int n0 = b << 7;
    int nloc = min(128, NN - n0);
    int beg = bbase[b], end = bbase[b + 1];
    if (t < 128) ldeg[t] = 0;
    __syncthreads();
    for (int i = beg + t; i < end; i += 256)
        atomicAdd(&ldeg[ebuf[i] & 127], 1);
    __syncthreads();
    int v = (t < nloc) ? ldeg[t] : 0;
    int incl;
    int excl = block_excl_scan<4>(v, t, &incl);
    if (t < nloc) {
        off[n0 + t]  = beg + excl + v;            // END offset convention
        float d = rsqrtf((float)(v + 1));         // +1 self-loop
        dinv[n0 + t] = d;
        ldinv[t] = d;
        lcur[t] = beg + excl;
    }
    __syncthreads();
    for (int i = beg + t; i < end; i += 256) {
        int e = ebuf[i];
        int pos = atomicAdd(&lcur[e & 127], 1);
        srows[pos] = (ushort_t)(e >> 7);
    }
    // fused: xs[row] = fp16(dinv[row] * x[row]) for this bucket's rows
    const float4* Xx = (const float4*)x;
#pragma unroll
    for (int i = 0; i < 8; ++i) {
        int f4 = t + i * 256;                     // 0..2047 (128 rows x 16 f4)
        int rloc = f4 >> 4, kq = f4 & 15;
        if (rloc < nloc) {
            float d = ldinv[rloc];
            float4 vv = Xx[(size_t)(n0 + rloc) * 16 + kq];
            __half2 h[2];
            h[0] = __floats2half2_rn(d * vv.x, d * vv.y);
            h[1] = __floats2half2_rn(d * vv.z, d * vv.w);
            ((float2*)xs)[(size_t)(n0 + rloc) * 16 + kq] = *(float2*)h;
        }
    }
}

// ---------------- FUSED gather + MFMA GEMM ----------------
// Block = 64 nodes. Wave w gathers rows [16w,16w+16) into the LDS X-tile
// (identical fp16 rounding to the old aggXh/aggHh path), then the block runs
// the gemm_mf MFMA phase. W-staging issues before the gather to hide latency.
// RS: out = fp16 rs[r]*relu(acc+b) row-major. POOL: run-length mean-pool
// atomics into Y=gsum by sorted batch. ZB: first 512 blocks zero zbuf (gsum).
template<int K, bool RS, bool POOL, bool ZB>
__global__ __launch_bounds__(256) void k_gg(const int* __restrict__ off,
                                            const ushort_t* __restrict__ srows,
                                            const float* __restrict__ dinv,
                                            const __half* __restrict__ SRC,
                                            const __half* __restrict__ WT,
                                            const float* __restrict__ bias,
                                            const float* __restrict__ rs,
                                            const int* __restrict__ batch,
                                            float* __restrict__ Y,
                                            float* __restrict__ zbuf,
                                            int M) {
    constexpr int KP = K + 8;       // padded fp16 row stride
    constexpr int NC = K / 8;       // 16B chunks per row
    constexpr int PL = NC / 8;      // chunks per lane (1 for 64, 2 for 128)
    __shared__ __half Xs[64 * KP];
    __shared__ __half Ws[128 * KP];
    __shared__ int sb[64];
    const int t = threadIdx.x;
    const int row0 = blockIdx.x * 64;

    if (ZB) {
        if (blockIdx.x < 512) zbuf[(blockIdx.x << 8) + t] = 0.f;
    }

    // stage WT (issues early; hides under the gather)
    const float4* W8 = (const float4*)WT;
#pragma unroll
    for (int i = t; i < 128 * NC; i += 256) {
        int n = i / NC, ch = i % NC;
        *(float4*)&Ws[n * KP + ch * 8] = W8[i];
    }
    if (POOL && t < 64) sb[t] = (row0 + t < M) ? batch[row0 + t] : -1;

    // ---- gather phase: wave w fills Xs rows [16w, 16w+16) ----
    const int w = t >> 6, l = t & 63;
    const int slot = l >> 3, q = l & 7;
    const float4* S4 = (const float4*)SRC;
    for (int i = 0; i < 16; ++i) {
        int rloc = 16 * w + i;
        int node = row0 + rloc;
        float acc[PL][8];
#pragma unroll
        for (int p = 0; p < PL; ++p)
#pragma unroll
            for (int j = 0; j < 8; ++j) acc[p][j] = 0.f;
        float di = 0.f;
        if (node < M) {
            int beg = node ? off[node - 1] : 0;
            int end = off[node];
            di = dinv[node];
            if (slot == 0) {
#pragma unroll
                for (int p = 0; p < PL; ++p) {
                    float4 raw = S4[(size_t)node * NC + p * 8 + q];
                    const __half2* h = (const __half2*)&raw;
#pragma unroll
                    for (int j = 0; j < 4; ++j) {
                        float2 f = __half22float2(h[j]);
                        acc[p][2 * j + 0] = f.x;
                        acc[p][2 * j + 1] = f.y;
                    }
                }
            }
            for (int e = beg + slot; e < end; e += 8) {
                int r = srows[e];
#pragma unroll
                for (int p = 0; p < PL; ++p) {
                    float4 raw = S4[(size_t)r * NC + p * 8 + q];
                    const __half2* h = (const __half2*)&raw;
#pragma unroll
                    for (int j = 0; j < 4; ++j) {
                        float2 f = __half22float2(h[j]);
                        acc[p][2 * j + 0] += f.x;
                        acc[p][2 * j + 1] += f.y;
                    }
                }
            }
        }
#pragma unroll
        for (int d = 8; d < 64; d <<= 1)
#pragma unroll
            for (int p = 0; p < PL; ++p)
#pragma unroll
                for (int j = 0; j < 8; ++j)
                    acc[p][j] += __shfl_xor(acc[p][j], d, 64);
        if (l < 8) {
#pragma unroll
            for (int p = 0; p < PL; ++p) {
                float4 pk;
                __half2* hp = (__half2*)&pk;
                hp[0] = __floats2half2_rn(di * acc[p][0], di * acc[p][1]);
                hp[1] = __floats2half2_rn(di * acc[p][2], di * acc[p][3]);
                hp[2] = __floats2half2_rn(di * acc[p][4], di * acc[p][5]);
                hp[3] = __floats2half2_rn(di * acc[p][6], di * acc[p][7]);
                *(float4*)&Xs[rloc * KP + (p * 8 + l) * 8] = pk;
            }
        }
    }
    __syncthreads();

    // ---- MFMA phase (identical to gemm_mf) ----
    const int lm = l & 15, lg = l >> 4;
    f32x4 macc[8];
#pragma unroll
    for (int c = 0; c < 8; ++c) macc[c] = (f32x4){0.f, 0.f, 0.f, 0.f};

#pragma unroll
    for (int kk = 0; kk < K / 32; ++kk) {
        f16x8 a = *(const f16x8*)&Xs[(16 * w + lm) * KP + kk * 32 + lg * 8];
#pragma unroll
        for (int c = 0; c < 8; ++c) {
            f16x8 bf = *(const f16x8*)&Ws[(16 * c + lm) * KP + kk * 32 + lg * 8];
            macc[c] = __builtin_amdgcn_mfma_f32_16x16x32_f16(a, bf, macc[c], 0, 0, 0);
        }
    }

    float bcol[8];
#pragma unroll
    for (int c = 0; c < 8; ++c) bcol[c] = bias[16 * c + lm];

    if (POOL) {
#pragma unroll
        for (int c = 0; c < 8; ++c) {
            int rung = -1;
            float run = 0.f;
#pragma unroll
            for (int j = 0; j < 4; ++j) {
                int rr = 16 * w + 4 * lg + j;
                int g = (row0 + rr < M) ? sb[rr] : -1;
                if (g != rung) {
                    if (rung >= 0) atomicAdd(&Y[rung * 128 + 16 * c + lm], run);
                    run = 0.f;
                    rung = g;
                }
                if (g >= 0) run += fmaxf(macc[c][j] + bcol[c], 0.f);
            }
            if (rung >= 0) atomicAdd(&Y[rung * 128 + 16 * c + lm], run);
        }
        return;
    }

    __half* Yh = (__half*)Y;
#pragma unroll
    for (int j = 0; j < 4; ++j) {
        int r = row0 + 16 * w + 4 * lg + j;
        if (r < M) {
            float d = RS ? rs[r] : 1.f;
#pragma unroll
            for (int c = 0; c < 8; ++c) {
                float v = d * fmaxf(macc[c][j] + bcol[c], 0.f);
                Yh[(size_t)r * 128 + 16 * c + lm] = __float2half(v);
            }
        }
    }
}

// ---------------- MFMA batched GEMM: {A,B}arr[c][g][t] = mean(GE) @ W1-half ----------------
__global__ __launch_bounds__(256) void gemm_bat(const float* __restrict__ gsum,
                                                const float* __restrict__ inv,
                                                const __half* __restrict__ Whl,
                                                float* __restrict__ Aarr,
                                                float* __restrict__ Barr) {
    constexpr int KP = 128 + 8;
    __shared__ __half Xs[64 * KP];
    __shared__ __half Ws[128 * KP];
    const int t = threadIdx.x;
    const int row0 = blockIdx.x * 64;
    const int y = blockIdx.y, z = blockIdx.z;

    const float4* G4 = (const float4*)gsum;
#pragma unroll
    for (int i = t; i < 64 * 16; i += 256) {
        int r = i >> 4, ch = i & 15;
        int g = row0 + r;
        float iv = inv[g];
        float4 a = G4[g * 32 + ch * 2];
        float4 b4 = G4[g * 32 + ch * 2 + 1];
        float4 pk;
        __half2* hp = (__half2*)&pk;
        hp[0] = __floats2half2_rn(iv * a.x, iv * a.y);
        hp[1] = __floats2half2_rn(iv * a.z, iv * a.w);
        hp[2] = __floats2half2_rn(iv * b4.x, iv * b4.y);
        hp[3] = __floats2half2_rn(iv * b4.z, iv * b4.w);
        *(float4*)&Xs[r * KP + ch * 8] = pk;
    }

    const int w  = t >> 6;
    const int l  = t & 63;
    const int lm = l & 15, lg = l >> 4;

    f32x4 acc[8];
#pragma unroll
    for (int c = 0; c < 8; ++c) acc[c] = (f32x4){0.f, 0.f, 0.f, 0.f};

    const float4* W8 = (const float4*)Whl;
#pragma unroll
    for (int pass = 0; pass < 2; ++pass) {
        __syncthreads();   // Xs ready (pass 0) / Ws no longer read (pass 1)
        size_t wbase = ((size_t)pass * 32 + z) * 256 * 16;  // f16x8 units
#pragma unroll
        for (int i = t; i < 128 * 16; i += 256) {
            int n = i >> 4, ch = i & 15;
            *(float4*)&Ws[n * KP + ch * 8] = W8[wbase + (size_t)(y * 128 + n) * 16 + ch];
        }
        __syncthreads();
#pragma unroll
        for (int kk = 0; kk < 4; ++kk) {
            f16x8 a = *(const f16x8*)&Xs[(16 * w + lm) * KP + kk * 32 + lg * 8];
#pragma unroll
            for (int c = 0; c < 8; ++c) {
                f16x8 bf = *(const f16x8*)&Ws[(16 * c + lm) * KP + kk * 32 + lg * 8];
                acc[c] = __builtin_amdgcn_mfma_f32_16x16x32_f16(a, bf, acc[c], 0, 0, 0);
            }
        }
    }

    float* Obase = (z & 1) ? Barr : Aarr;
#pragma unroll
    for (int j = 0; j < 4; ++j) {
        int g = row0 + 16 * w + 4 * lg + j;
        size_t rb = ((size_t)(z >> 1) * NG + g) * HID + y * 128;
#pragma unroll
        for (int c = 0; c < 8; ++c)
            Obase[rb + 16 * c + lm] = acc[c][j];
    }
}

// ---------------- pair epilogue ----------------
__global__ __launch_bounds__(256) void k_pair(const float* __restrict__ Aarr,
                                              const float* __restrict__ Barr,
                                              const int* __restrict__ ddb,
                                              const int* __restrict__ ecl,
                                              const float* __restrict__ B1,
                                              const float* __restrict__ W2,
                                              const float* __restrict__ B2,
                                              float* __restrict__ out) {
    int p = blockIdx.x * 4 + (threadIdx.x >> 6);
    int lane = threadIdx.x & 63;
    int c = ecl[p];
    int a = ddb[p];
    int b = ddb[NP + p];
    const float4* rA = (const float4*)&Aarr[((size_t)c * NG + a) * HID];
    const float4* rB = (const float4*)&Barr[((size_t)c * NG + b) * HID];
    const float4* b1 = (const float4*)&B1[c * HID];
    const float4* w2 = (const float4*)&W2[c * HID];
    float4 va = rA[lane], vb = rB[lane], v1 = b1[lane], v2 = w2[lane];
    float hx = va.x + vb.x + v1.x;
    float hy = va.y + vb.y + v1.y;
    float hz = va.z + vb.z + v1.z;
    float hw = va.w + vb.w + v1.w;
    float s = 0.f;
    s = fmaf(hx > 0.f ? hx : 0.f, v2.x, s);
    s = fmaf(hy > 0.f ? hy : 0.f, v2.y, s);
    s = fmaf(hz > 0.f ? hz : 0.f, v2.z, s);
    s = fmaf(hw > 0.f ? hw : 0.f, v2.w, s);
    for (int o = 32; o; o >>= 1) s += __shfl_down(s, o, 64);
    if (lane == 0) out[p] = s + B2[c];
}

// ---------------- launch ----------------
extern "C" void kernel_launch(void* const* d_in, const int* in_sizes, int n_in,
                              void* d_out, int out_size, void* d_ws, size_t ws_size,
                              hipStream_t stream) {
    const float* x    = (const float*)d_in[0];
    const float* c1w  = (const float*)d_in[1];
    const float* c1b  = (const float*)d_in[2];
    const float* c2w  = (const float*)d_in[3];
    const float* c2b  = (const float*)d_in[4];
    const float* rw1  = (const float*)d_in[5];
    const float* rb1  = (const float*)d_in[6];
    const float* rw2  = (const float*)d_in[7];
    const float* rb2  = (const float*)d_in[8];
    const int*   eidx = (const int*)d_in[9];    // [2, NE]: rows then cols
    const int*   batch= (const int*)d_in[10];
    const int*   ddb  = (const int*)d_in[11];   // [2, NP]
    const int*   ecl  = (const int*)d_in[12];
    float* out = (float*)d_out;

    // ---- workspace layout (floats) ----
    // off(50048) | srows(NE ints; used as NE ushorts) | dinv(50048) | bufA(6.4M) | bufB(6.4M)
    // temporal aliases:
    //   ebuf  (int NE)          -> bufA[0..0.8M)      (k_part .. k_bsort)
    //   cnt/btot/bbase          -> bufB[1.7M..1.86M)  (k_prep0 .. k_bsort)
    //   xs    (fp16 [NN][64])   -> bufB[0..1.6M)      (k_bsort .. k_gg1)
    //   H1h   (fp16 [NN][128])  -> bufA[0..3.2M)      (k_gg1 .. k_gg2)   [disjoint from xs]
    //   gsum  (f32 131072)      -> bufA[4.5M..4.63M)  (zeroed in k_gg1; k_gg2 .. gemm_bat)
    //   w1t   (fp16 [128][64])  -> bufA[4.70M..)      (k_prep0 .. k_gg1)
    //   w2t   (fp16 [128][128]) -> bufA[4.71M..)      (k_prep0 .. k_gg2)
    //   inv   (f32 1024)        -> bufA[4.73M..)      (k_prep0 .. gemm_bat)
    //   Whl   (fp16 2x1.05M)    -> bufB[4.3M..5.35M)  (k_prep0 .. gemm_bat)
    //   Aarr  (f32 4.19M)       -> bufA[0..4.19M)     (gemm_bat .. k_pair)
    //   Barr  (f32 4.19M)       -> bufB[0..4.19M)     (gemm_bat .. k_pair)
    int*   off   = (int*)d_ws;
    int*   srows = off + 50048;
    float* dinv  = (float*)(srows + NE);
    float* bufA  = dinv + 50048;
    float* bufB  = bufA + NN * EMB;

    int*      ebuf  = (int*)bufA;
    int*      cnt   = (int*)(bufB + 1700000);
    int*      btot  = cnt + NB * NCHUNK;
    int*      bbase = btot + 512;
    __half*   xs    = (__half*)bufB;
    __half*   H1h   = (__half*)bufA;
    float*    gsum  = bufA + 4500000;
    __half*   w1t   = (__half*)(bufA + 4700000);
    __half*   w2t   = (__half*)(bufA + 4710000);
    float*    inv   = bufA + 4730000;
    __half*   Whl   = (__half*)(bufB + 4300000);
    float*    Aarr  = bufA;
    float*    Barr  = bufB;
    ushort_t* srowsU = (ushort_t*)srows;

    const int* erow = eidx;
    const int* ecol = eidx + NE;

    // ---- fused prep: edge histogram + weight fp16 tables + graph inv-counts ----
    k_prep0<<<1012, 256, 0, stream>>>(ecol, c1w, c2w, rw1, batch,
                                      cnt, w1t, w2t, Whl, inv);

    // ---- CSR build ----
    k_bscan<<<NB,  512, 0, stream>>>(cnt, btot);
    k_part <<<NCHUNK, 256, 0, stream>>>(erow, ecol, cnt, btot, bbase, ebuf);
    k_bsort<<<NB,  256, 0, stream>>>(ebuf, bbase, x, off, dinv, srowsU, xs);

    // ---- layer 1 (fused gather+GEMM): H1h = fp16(dinv*relu(gather(xs)@W1+b1)) ----
    k_gg<INCH,true,false,true><<<CDIV(NN,64),256,0,stream>>>(
        off, srowsU, dinv, xs, w1t, c1b, dinv, nullptr, (float*)H1h, gsum, NN);

    // ---- layer 2 (fused gather+GEMM+pool): gsum += pooled relu(gather(H1h)@W2+b2) ----
    k_gg<EMB,false,true,false><<<CDIV(NN,64),256,0,stream>>>(
        off, srowsU, dinv, H1h, w2t, c2b, nullptr, batch, gsum, nullptr, NN);

    // ---- regressor: MFMA {A,B} tables (hi+lo compensated, mean folded), pair epilogue ----
    dim3 bgrid(NG/64, 2, 2*NCL);
    gemm_bat<<<bgrid,256,0,stream>>>(gsum, inv, Whl, Aarr, Barr);
    k_pair<<<NP/4,256,0,stream>>>(Aarr, Barr, ddb, ecl, rb1, rw2, rb2, out);
}

// Round 17
// 157.378 us; speedup vs baseline: 1.3335x; 1.3335x over previous
//
#include <hip/hip_runtime.h>
#include <hip/hip_fp16.h>

#define NN 50000     // nodes
#define NE 800000    // edges
#define NG 1024      // graphs
#define NP 16384     // pairs
#define NCL 16       // cell lines
#define INCH 64
#define EMB 128
#define HID 256

#define NB 391       // node buckets of 128 (CDIV(NN,128))
#define NCHUNK 400   // edge chunks
#define EPB 2000     // edges per chunk (NE = 400*2000 exactly)

#define CDIV(a,b) (((a)+(b)-1)/(b))

typedef _Float16 f16x8 __attribute__((ext_vector_type(8)));
typedef float    f32x4 __attribute__((ext_vector_type(4)));
typedef unsigned short ushort_t;

// ---------------- block exclusive scan (NW waves) ----------------
template<int NW>
__device__ __forceinline__ int block_excl_scan(int v, int t, int* incl_out) {
    int lane = t & 63, w = t >> 6;
    int s = v;
#pragma unroll
    for (int d = 1; d < 64; d <<= 1) {
        int u = __shfl_up(s, d, 64);
        if (lane >= d) s += u;
    }
    __shared__ int wsum[NW];
    if (lane == 63) wsum[w] = s;
    __syncthreads();
    int add = 0;
    for (int k = 0; k < w; ++k) add += wsum[k];
    *incl_out = s + add;
    return s + add - v;
}

// ---------------- fused prep+cnt ----------------
// blocks [0,400): edge-chunk histogram; [400,912): Whl hi/lo; [912,944): w1t;
// [944,1008): w2t; [1008,1012): inv counts.
__global__ __launch_bounds__(256) void k_prep0(const int* __restrict__ cols,
                                               const float* __restrict__ c1w,
                                               const float* __restrict__ c2w,
                                               const float* __restrict__ rw1,
                                               const int* __restrict__ batch,
                                               int* __restrict__ cnt,
                                               __half* __restrict__ w1t,
                                               __half* __restrict__ w2t,
                                               __half* __restrict__ Whl,
                                               float* __restrict__ inv) {
    __shared__ int hist[NB];
    int bid = blockIdx.x, t = threadIdx.x;
    if (bid < 400) {
        int ch = bid;
        for (int b = t; b < NB; b += 256) hist[b] = 0;
        __syncthreads();
        for (int e = ch * EPB + t; e < (ch + 1) * EPB; e += 256)
            atomicAdd(&hist[cols[e] >> 7], 1);
        __syncthreads();
        for (int b = t; b < NB; b += 256) cnt[b * NCHUNK + ch] = hist[b];
    } else if (bid < 912) {
        int i = (bid - 400) * 256 + t;            // 0..131071 chunk-units
        int ch = i & 15, tg = (i >> 4) & 255, z = i >> 12;
        int c = z >> 1, part = z & 1;
        f16x8 hi, lo;
#pragma unroll
        for (int j = 0; j < 8; ++j) {
            float v = rw1[(size_t)c * 65536 + (size_t)(part * 128 + ch * 8 + j) * 256 + tg];
            _Float16 h = (_Float16)v;
            hi[j] = h;
            lo[j] = (_Float16)(v - (float)h);
        }
        size_t base = ((size_t)z * 256 + tg) * 16 + ch;
        ((f16x8*)Whl)[base] = hi;
        ((f16x8*)Whl)[(size_t)32 * 256 * 16 + base] = lo;
    } else if (bid < 944) {
        int i = (bid - 912) * 256 + t;            // 0..8191
        int k = i >> 7, n = i & 127;
        w1t[n * INCH + k] = __float2half(c1w[i]);
    } else if (bid < 1008) {
        int i = (bid - 944) * 256 + t;            // 0..16383
        int k = i >> 7, n = i & 127;
        w2t[n * EMB + k] = __float2half(c2w[i]);
    } else {
        int g = (bid - 1008) * 256 + t;           // 0..1023
        int lo_ = 0, hi_ = NN;
        while (lo_ < hi_) { int m = (lo_ + hi_) >> 1; if (batch[m] < g) lo_ = m + 1; else hi_ = m; }
        int s = lo_;
        lo_ = 0; hi_ = NN;
        while (lo_ < hi_) { int m = (lo_ + hi_) >> 1; if (batch[m] < g + 1) lo_ = m + 1; else hi_ = m; }
        float c = (float)(lo_ - s);
        inv[g] = 1.f / fmaxf(c, 1.f);
    }
}

// ---------------- Pass B: per-bucket scan over chunks -> cnt excl, btot ----------------
__global__ __launch_bounds__(512) void k_bscan(int* __restrict__ cnt,
                                               int* __restrict__ btot) {
    int b = blockIdx.x, t = threadIdx.x;
    int v = (t < NCHUNK) ? cnt[b * NCHUNK + t] : 0;
    int incl;
    int excl = block_excl_scan<8>(v, t, &incl);
    if (t < NCHUNK) cnt[b * NCHUNK + t] = excl;
    if (t == NCHUNK - 1) btot[b] = incl;
}

// ---------------- Pass C: partition edges; bbase computed in-block ----------------
__global__ __launch_bounds__(256) void k_part(const int* __restrict__ rows,
                                              const int* __restrict__ cols,
                                              const int* __restrict__ cnt,
                                              const int* __restrict__ btot,
                                              int* __restrict__ bbase_out,
                                              int* __restrict__ ebuf) {
    __shared__ int bb[NB + 1];
    __shared__ int cur[NB];
    __shared__ int S0s;
    int ch = blockIdx.x, t = threadIdx.x;
    int incl;
    int v0 = btot[t];
    int e0 = block_excl_scan<4>(v0, t, &incl);
    bb[t] = e0;
    if (t == 255) S0s = incl;
    __syncthreads();
    int t2 = t + 256;
    int v1 = (t2 < NB) ? btot[t2] : 0;
    int e1 = block_excl_scan<4>(v1, t, &incl);
    if (t2 <= NB) bb[t2] = e1 + S0s;
    __syncthreads();
    for (int b = t; b < NB; b += 256) cur[b] = bb[b] + cnt[b * NCHUNK + ch];
    if (ch == 0)
        for (int i = t; i <= NB; i += 256) bbase_out[i] = bb[i];
    __syncthreads();
    for (int e = ch * EPB + t; e < (ch + 1) * EPB; e += 256) {
        int c = cols[e], r = rows[e];
        int pos = atomicAdd(&cur[c >> 7], 1);
        ebuf[pos] = (r << 7) | (c & 127);
    }
}

// ---------------- Pass D: bucket counting sort -> srows(ushort)/off/dinv + x->fp16 ----------------
__global__ __launch_bounds__(256) void k_bsort(const int* __restrict__ ebuf,
                                               const int* __restrict__ bbase,
                                               const float* __restrict__ x,
                                               int* __restrict__ off,
                                               float* __restrict__ dinv,
                                               ushort_t* __restrict__ srows,
                                               __half* __restrict__ xs) {
    __shared__ int   ldeg[128];
    __shared__ int   lcur[128];
    __shared__ float ldinv[128];
    int b = blockIdx.x, t = threadIdx.x;
    int n0 = b << 7;
    int nloc = min(128, NN - n0);
    int beg = bbase[b], end = bbase[b + 1];
    if (t < 128) ldeg[t] = 0;
    __syncthreads();
    for (int i = beg + t; i < end; i += 256)
        atomicAdd(&ldeg[ebuf[i] & 127], 1);
    __syncthreads();
    int v = (t < nloc) ? ldeg[t] : 0;
    int incl;
    int excl = block_excl_scan<4>(v, t, &incl);
    if (t < nloc) {
        off[n0 + t]  = beg + excl + v;            // END offset convention
        float d = rsqrtf((float)(v + 1));         // +1 self-loop
        dinv[n0 + t] = d;
        ldinv[t] = d;
        lcur[t] = beg + excl;
    }
    __syncthreads();
    for (int i = beg + t; i < end; i += 256) {
        int e = ebuf[i];
        int pos = atomicAdd(&lcur[e & 127], 1);
        srows[pos] = (ushort_t)(e >> 7);
    }
    // fused: xs[row] = fp16(dinv[row] * x[row]) for this bucket's rows
    const float4* Xx = (const float4*)x;
#pragma unroll
    for (int i = 0; i < 8; ++i) {
        int f4 = t + i * 256;                     // 0..2047 (128 rows x 16 f4)
        int rloc = f4 >> 4, kq = f4 & 15;
        if (rloc < nloc) {
            float d = ldinv[rloc];
            float4 vv = Xx[(size_t)(n0 + rloc) * 16 + kq];
            __half2 h[2];
            h[0] = __floats2half2_rn(d * vv.x, d * vv.y);
            h[1] = __floats2half2_rn(d * vv.z, d * vv.w);
            ((float2*)xs)[(size_t)(n0 + rloc) * 16 + kq] = *(float2*)h;
        }
    }
}

// ---------------- gather on pre-scaled fp16 rows, fp16 output ----------------
// SRC' (fp16) scaled by dinv[row]; DST[c] = fp16(dinv[c]*(sum_e SRC'[r] + SRC'[c])).
// ZB: first 512 blocks also zero zbuf[131072] (gsum).
template<int FEAT, bool ZB>
__global__ __launch_bounds__(256) void k_gath_h(const int* __restrict__ off,
                                                const ushort_t* __restrict__ srows,
                                                const float* __restrict__ dinv,
                                                const __half* __restrict__ SRC,
                                                __half* __restrict__ DST,
                                                float* __restrict__ zbuf) {
    if (ZB) {
        if (blockIdx.x < 512) zbuf[(blockIdx.x << 8) + threadIdx.x] = 0.f;
    }
    constexpr int NC = FEAT / 8;    // 16B chunks (8 halfs) per row
    constexpr int PL = NC / 8;      // chunks per lane (1 for 64, 2 for 128)
    int node = blockIdx.x * 4 + (threadIdx.x >> 6);
    int lane = threadIdx.x & 63;
    int slot = lane >> 3, q = lane & 7;
    if (node >= NN) return;
    int beg = node ? off[node - 1] : 0;
    int end = off[node];
    float di = dinv[node];
    const float4* S4 = (const float4*)SRC;

    float acc[PL][8];
#pragma unroll
    for (int i = 0; i < PL; ++i)
#pragma unroll
        for (int j = 0; j < 8; ++j) acc[i][j] = 0.f;

    if (slot == 0) {
#pragma unroll
        for (int i = 0; i < PL; ++i) {
            float4 raw = S4[node * NC + i * 8 + q];
            const __half2* h = (const __half2*)&raw;
#pragma unroll
            for (int j = 0; j < 4; ++j) {
                float2 f = __half22float2(h[j]);
                acc[i][2 * j + 0] = f.x;
                acc[i][2 * j + 1] = f.y;
            }
        }
    }
    for (int e = beg + slot; e < end; e += 8) {
        int r = srows[e];
#pragma unroll
        for (int i = 0; i < PL; ++i) {
            float4 raw = S4[r * NC + i * 8 + q];
            const __half2* h = (const __half2*)&raw;
#pragma unroll
            for (int j = 0; j < 4; ++j) {
                float2 f = __half22float2(h[j]);
                acc[i][2 * j + 0] += f.x;
                acc[i][2 * j + 1] += f.y;
            }
        }
    }
#pragma unroll
    for (int d = 8; d < 64; d <<= 1)
#pragma unroll
        for (int i = 0; i < PL; ++i)
#pragma unroll
            for (int j = 0; j < 8; ++j)
                acc[i][j] += __shfl_xor(acc[i][j], d, 64);

    if (lane < 8) {
        float4* D4 = (float4*)DST;   // 8 halfs per float4
#pragma unroll
        for (int i = 0; i < PL; ++i) {
            float4 pk;
            __half2* hp = (__half2*)&pk;
            hp[0] = __floats2half2_rn(di * acc[i][0], di * acc[i][1]);
            hp[1] = __floats2half2_rn(di * acc[i][2], di * acc[i][3]);
            hp[2] = __floats2half2_rn(di * acc[i][4], di * acc[i][5]);
            hp[3] = __floats2half2_rn(di * acc[i][6], di * acc[i][7]);
            D4[node * NC + i * 8 + lane] = pk;
        }
    }
}

// ---------------- MFMA node GEMM: Y[M,128] = X[M,K](fp16) @ W + bias, relu ----------------
template<int K, bool RS, bool POOL>
__global__ __launch_bounds__(256) void gemm_mf(const __half* __restrict__ X,
                                               const __half* __restrict__ WT,
                                               const float* __restrict__ bias,
                                               const float* __restrict__ rs,
                                               const int* __restrict__ batch,
                                               float* __restrict__ Y, int M) {
    constexpr int KP = K + 8;                 // padded fp16 row stride (16B-aligned)
    __shared__ __half Xs[64 * KP];
    __shared__ __half Ws[128 * KP];
    __shared__ int sb[64];
    const int t = threadIdx.x;
    const int row0 = blockIdx.x * 64;

    const float4* X8 = (const float4*)X;
#pragma unroll
    for (int i = t; i < 64 * (K / 8); i += 256) {
        int r = i / (K / 8), ch = i % (K / 8);
        float4 v = make_float4(0.f, 0.f, 0.f, 0.f);
        if (row0 + r < M) v = X8[(size_t)(row0 + r) * (K / 8) + ch];
        *(float4*)&Xs[r * KP + ch * 8] = v;
    }
    const float4* W8 = (const float4*)WT;
#pragma unroll
    for (int i = t; i < 128 * (K / 8); i += 256) {
        int n = i / (K / 8), ch = i % (K / 8);
        *(float4*)&Ws[n * KP + ch * 8] = W8[i];
    }
    if (POOL) {
        if (t < 64) sb[t] = (row0 + t < M) ? batch[row0 + t] : -1;
    }
    __syncthreads();

    const int w  = t >> 6;
    const int l  = t & 63;
    const int lm = l & 15, lg = l >> 4;

    f32x4 acc[8];
#pragma unroll
    for (int c = 0; c < 8; ++c) acc[c] = (f32x4){0.f, 0.f, 0.f, 0.f};

#pragma unroll
    for (int kk = 0; kk < K / 32; ++kk) {
        f16x8 a = *(const f16x8*)&Xs[(16 * w + lm) * KP + kk * 32 + lg * 8];
#pragma unroll
        for (int c = 0; c < 8; ++c) {
            f16x8 bf = *(const f16x8*)&Ws[(16 * c + lm) * KP + kk * 32 + lg * 8];
            acc[c] = __builtin_amdgcn_mfma_f32_16x16x32_f16(a, bf, acc[c], 0, 0, 0);
        }
    }

    float bcol[8];
#pragma unroll
    for (int c = 0; c < 8; ++c) bcol[c] = bias[16 * c + lm];

    if (POOL) {
#pragma unroll
        for (int c = 0; c < 8; ++c) {
            int rung = -1;
            float run = 0.f;
#pragma unroll
            for (int j = 0; j < 4; ++j) {
                int rr = 16 * w + 4 * lg + j;
                int g = (row0 + rr < M) ? sb[rr] : -1;
                if (g != rung) {
                    if (rung >= 0) atomicAdd(&Y[rung * 128 + 16 * c + lm], run);
                    run = 0.f;
                    rung = g;
                }
                if (g >= 0) run += fmaxf(acc[c][j] + bcol[c], 0.f);
            }
            if (rung >= 0) atomicAdd(&Y[rung * 128 + 16 * c + lm], run);
        }
        return;
    }

    __half* Yh = (__half*)Y;
#pragma unroll
    for (int j = 0; j < 4; ++j) {
        int r = row0 + 16 * w + 4 * lg + j;
        if (r < M) {
            float d = RS ? rs[r] : 1.f;
#pragma unroll
            for (int c = 0; c < 8; ++c) {
                float v = d * fmaxf(acc[c][j] + bcol[c], 0.f);
                Yh[(size_t)r * 128 + 16 * c + lm] = __float2half(v);
            }
        }
    }
}

// ---------------- MFMA batched GEMM: {A,B}arr[c][g][t] = mean(GE) @ W1-half ----------------
__global__ __launch_bounds__(256) void gemm_bat(const float* __restrict__ gsum,
                                                const float* __restrict__ inv,
                                                const __half* __restrict__ Whl,
                                                float* __restrict__ Aarr,
                                                float* __restrict__ Barr) {
    constexpr int KP = 128 + 8;
    __shared__ __half Xs[64 * KP];
    __shared__ __half Ws[128 * KP];
    const int t = threadIdx.x;
    const int row0 = blockIdx.x * 64;
    const int y = blockIdx.y, z = blockIdx.z;

    const float4* G4 = (const float4*)gsum;
#pragma unroll
    for (int i = t; i < 64 * 16; i += 256) {
        int r = i >> 4, ch = i & 15;
        int g = row0 + r;
        float iv = inv[g];
        float4 a = G4[g * 32 + ch * 2];
        float4 b4 = G4[g * 32 + ch * 2 + 1];
        float4 pk;
        __half2* hp = (__half2*)&pk;
        hp[0] = __floats2half2_rn(iv * a.x, iv * a.y);
        hp[1] = __floats2half2_rn(iv * a.z, iv * a.w);
        hp[2] = __floats2half2_rn(iv * b4.x, iv * b4.y);
        hp[3] = __floats2half2_rn(iv * b4.z, iv * b4.w);
        *(float4*)&Xs[r * KP + ch * 8] = pk;
    }

    const int w  = t >> 6;
    const int l  = t & 63;
    const int lm = l & 15, lg = l >> 4;

    f32x4 acc[8];
#pragma unroll
    for (int c = 0; c < 8; ++c) acc[c] = (f32x4){0.f, 0.f, 0.f, 0.f};

    const float4* W8 = (const float4*)Whl;
#pragma unroll
    for (int pass = 0; pass < 2; ++pass) {
        __syncthreads();   // Xs ready (pass 0) / Ws no longer read (pass 1)
        size_t wbase = ((size_t)pass * 32 + z) * 256 * 16;  // f16x8 units
#pragma unroll
        for (int i = t; i < 128 * 16; i += 256) {
            int n = i >> 4, ch = i & 15;
            *(float4*)&Ws[n * KP + ch * 8] = W8[wbase + (size_t)(y * 128 + n) * 16 + ch];
        }
        __syncthreads();
#pragma unroll
        for (int kk = 0; kk < 4; ++kk) {
            f16x8 a = *(const f16x8*)&Xs[(16 * w + lm) * KP + kk * 32 + lg * 8];
#pragma unroll
            for (int c = 0; c < 8; ++c) {
                f16x8 bf = *(const f16x8*)&Ws[(16 * c + lm) * KP + kk * 32 + lg * 8];
                acc[c] = __builtin_amdgcn_mfma_f32_16x16x32_f16(a, bf, acc[c], 0, 0, 0);
            }
        }
    }

    float* Obase = (z & 1) ? Barr : Aarr;
#pragma unroll
    for (int j = 0; j < 4; ++j) {
        int g = row0 + 16 * w + 4 * lg + j;
        size_t rb = ((size_t)(z >> 1) * NG + g) * HID + y * 128;
#pragma unroll
        for (int c = 0; c < 8; ++c)
            Obase[rb + 16 * c + lm] = acc[c][j];
    }
}

// ---------------- pair epilogue ----------------
__global__ __launch_bounds__(256) void k_pair(const float* __restrict__ Aarr,
                                              const float* __restrict__ Barr,
                                              const int* __restrict__ ddb,
                                              const int* __restrict__ ecl,
                                              const float* __restrict__ B1,
                                              const float* __restrict__ W2,
                                              const float* __restrict__ B2,
                                              float* __restrict__ out) {
    int p = blockIdx.x * 4 + (threadIdx.x >> 6);
    int lane = threadIdx.x & 63;
    int c = ecl[p];
    int a = ddb[p];
    int b = ddb[NP + p];
    const float4* rA = (const float4*)&Aarr[((size_t)c * NG + a) * HID];
    const float4* rB = (const float4*)&Barr[((size_t)c * NG + b) * HID];
    const float4* b1 = (const float4*)&B1[c * HID];
    const float4* w2 = (const float4*)&W2[c * HID];
    float4 va = rA[lane], vb = rB[lane], v1 = b1[lane], v2 = w2[lane];
    float hx = va.x + vb.x + v1.x;
    float hy = va.y + vb.y + v1.y;
    float hz = va.z + vb.z + v1.z;
    float hw = va.w + vb.w + v1.w;
    float s = 0.f;
    s = fmaf(hx > 0.f ? hx : 0.f, v2.x, s);
    s = fmaf(hy > 0.f ? hy : 0.f, v2.y, s);
    s = fmaf(hz > 0.f ? hz : 0.f, v2.z, s);
    s = fmaf(hw > 0.f ? hw : 0.f, v2.w, s);
    for (int o = 32; o; o >>= 1) s += __shfl_down(s, o, 64);
    if (lane == 0) out[p] = s + B2[c];
}

// ---------------- launch ----------------
extern "C" void kernel_launch(void* const* d_in, const int* in_sizes, int n_in,
                              void* d_out, int out_size, void* d_ws, size_t ws_size,
                              hipStream_t stream) {
    const float* x    = (const float*)d_in[0];
    const float* c1w  = (const float*)d_in[1];
    const float* c1b  = (const float*)d_in[2];
    const float* c2w  = (const float*)d_in[3];
    const float* c2b  = (const float*)d_in[4];
    const float* rw1  = (const float*)d_in[5];
    const float* rb1  = (const float*)d_in[6];
    const float* rw2  = (const float*)d_in[7];
    const float* rb2  = (const float*)d_in[8];
    const int*   eidx = (const int*)d_in[9];    // [2, NE]: rows then cols
    const int*   batch= (const int*)d_in[10];
    const int*   ddb  = (const int*)d_in[11];   // [2, NP]
    const int*   ecl  = (const int*)d_in[12];
    float* out = (float*)d_out;

    // ---- workspace layout (floats) ----
    // off(50048) | srows(NE ints; used as NE ushorts) | dinv(50048) | bufA(6.4M) | bufB(6.4M)
    int*   off   = (int*)d_ws;
    int*   srows = off + 50048;
    float* dinv  = (float*)(srows + NE);
    float* bufA  = dinv + 50048;
    float* bufB  = bufA + NN * EMB;

    int*      ebuf  = (int*)bufA;
    int*      cnt   = (int*)(bufB + 1700000);
    int*      btot  = cnt + NB * NCHUNK;
    int*      bbase = btot + 512;
    __half*   xs    = (__half*)bufB;
    __half*   aggXh = (__half*)bufA;
    __half*   H1h   = (__half*)bufB;
    __half*   aggHh = (__half*)bufA;
    float*    gsum  = bufA + 4500000;
    __half*   w1t   = (__half*)(bufA + 4700000);
    __half*   w2t   = (__half*)(bufA + 4710000);
    float*    inv   = bufA + 4730000;
    __half*   Whl   = (__half*)(bufB + 4300000);
    float*    Aarr  = bufA;
    float*    Barr  = bufB;
    ushort_t* srowsU = (ushort_t*)srows;

    const int* erow = eidx;
    const int* ecol = eidx + NE;

    // ---- fused prep: edge histogram + weight fp16 tables + graph inv-counts ----
    k_prep0<<<1012, 256, 0, stream>>>(ecol, c1w, c2w, rw1, batch,
                                      cnt, w1t, w2t, Whl, inv);

    // ---- CSR build ----
    k_bscan<<<NB,  512, 0, stream>>>(cnt, btot);
    k_part <<<NCHUNK, 256, 0, stream>>>(erow, ecol, cnt, btot, bbase, ebuf);
    k_bsort<<<NB,  256, 0, stream>>>(ebuf, bbase, x, off, dinv, srowsU, xs);

    // ---- layer 1: aggX(fp16) = gather(xs) [+ zero gsum] ; H1'(fp16) = dinv*relu(aggX@W1+b1) ----
    k_gath_h<INCH,true><<<CDIV(NN,4),256,0,stream>>>(off, srowsU, dinv, xs, aggXh, gsum);
    gemm_mf<INCH,true,false><<<CDIV(NN,64),256,0,stream>>>(aggXh, w1t, c1b, dinv, nullptr, (float*)H1h, NN);

    // ---- layer 2: aggH(fp16) = gather(H1') ; MFMA gemm2 + fused mean-pool atomics ----
    k_gath_h<EMB,false><<<CDIV(NN,4),256,0,stream>>>(off, srowsU, dinv, H1h, aggHh, nullptr);
    gemm_mf<EMB,false,true><<<CDIV(NN,64),256,0,stream>>>(aggHh, w2t, c2b, nullptr, batch, gsum, NN);

    // ---- regressor: MFMA {A,B} tables (hi+lo compensated, mean folded), pair epilogue ----
    dim3 bgrid(NG/64, 2, 2*NCL);
    gemm_bat<<<bgrid,256,0,stream>>>(gsum, inv, Whl, Aarr, Barr);
    k_pair<<<NP/4,256,0,stream>>>(Aarr, Barr, ddb, ecl, rb1, rw2, rb2, out);
}

// Round 18
// 155.395 us; speedup vs baseline: 1.3505x; 1.0128x over previous
//
#include <hip/hip_runtime.h>
#include <hip/hip_fp16.h>

#define NN 50000     // nodes
#define NE 800000    // edges
#define NG 1024      // graphs
#define NP 16384     // pairs
#define NCL 16       // cell lines
#define INCH 64
#define EMB 128
#define HID 256

#define NB 391       // node buckets of 128 (CDIV(NN,128))
#define NCHUNK 400   // edge chunks
#define EPB 2000     // edges per chunk (NE = 400*2000 exactly)

#define CDIV(a,b) (((a)+(b)-1)/(b))

typedef _Float16 f16x8 __attribute__((ext_vector_type(8)));
typedef float    f32x4 __attribute__((ext_vector_type(4)));
typedef unsigned short ushort_t;

// ---------------- block exclusive scan (NW waves) ----------------
template<int NW>
__device__ __forceinline__ int block_excl_scan(int v, int t, int* incl_out) {
    int lane = t & 63, w = t >> 6;
    int s = v;
#pragma unroll
    for (int d = 1; d < 64; d <<= 1) {
        int u = __shfl_up(s, d, 64);
        if (lane >= d) s += u;
    }
    __shared__ int wsum[NW];
    if (lane == 63) wsum[w] = s;
    __syncthreads();
    int add = 0;
    for (int k = 0; k < w; ++k) add += wsum[k];
    *incl_out = s + add;
    return s + add - v;
}

// ---------------- fused prep+cnt ----------------
// blocks [0,400): edge-chunk histogram; [400,912): Whl hi/lo; [912,944): w1t;
// [944,1008): w2t; [1008,1012): inv counts.
__global__ __launch_bounds__(256) void k_prep0(const int* __restrict__ cols,
                                               const float* __restrict__ c1w,
                                               const float* __restrict__ c2w,
                                               const float* __restrict__ rw1,
                                               const int* __restrict__ batch,
                                               int* __restrict__ cnt,
                                               __half* __restrict__ w1t,
                                               __half* __restrict__ w2t,
                                               __half* __restrict__ Whl,
                                               float* __restrict__ inv) {
    __shared__ int hist[NB];
    int bid = blockIdx.x, t = threadIdx.x;
    if (bid < 400) {
        int ch = bid;
        for (int b = t; b < NB; b += 256) hist[b] = 0;
        __syncthreads();
        for (int e = ch * EPB + t; e < (ch + 1) * EPB; e += 256)
            atomicAdd(&hist[cols[e] >> 7], 1);
        __syncthreads();
        for (int b = t; b < NB; b += 256) cnt[b * NCHUNK + ch] = hist[b];
    } else if (bid < 912) {
        int i = (bid - 400) * 256 + t;            // 0..131071 chunk-units
        int ch = i & 15, tg = (i >> 4) & 255, z = i >> 12;
        int c = z >> 1, part = z & 1;
        f16x8 hi, lo;
#pragma unroll
        for (int j = 0; j < 8; ++j) {
            float v = rw1[(size_t)c * 65536 + (size_t)(part * 128 + ch * 8 + j) * 256 + tg];
            _Float16 h = (_Float16)v;
            hi[j] = h;
            lo[j] = (_Float16)(v - (float)h);
        }
        size_t base = ((size_t)z * 256 + tg) * 16 + ch;
        ((f16x8*)Whl)[base] = hi;
        ((f16x8*)Whl)[(size_t)32 * 256 * 16 + base] = lo;
    } else if (bid < 944) {
        int i = (bid - 912) * 256 + t;            // 0..8191
        int k = i >> 7, n = i & 127;
        w1t[n * INCH + k] = __float2half(c1w[i]);
    } else if (bid < 1008) {
        int i = (bid - 944) * 256 + t;            // 0..16383
        int k = i >> 7, n = i & 127;
        w2t[n * EMB + k] = __float2half(c2w[i]);
    } else {
        int g = (bid - 1008) * 256 + t;           // 0..1023
        int lo_ = 0, hi_ = NN;
        while (lo_ < hi_) { int m = (lo_ + hi_) >> 1; if (batch[m] < g) lo_ = m + 1; else hi_ = m; }
        int s = lo_;
        lo_ = 0; hi_ = NN;
        while (lo_ < hi_) { int m = (lo_ + hi_) >> 1; if (batch[m] < g + 1) lo_ = m + 1; else hi_ = m; }
        float c = (float)(lo_ - s);
        inv[g] = 1.f / fmaxf(c, 1.f);
    }
}

// ---------------- Pass B: per-bucket scan over chunks -> cnt excl, btot ----------------
__global__ __launch_bounds__(512) void k_bscan(int* __restrict__ cnt,
                                               int* __restrict__ btot) {
    int b = blockIdx.x, t = threadIdx.x;
    int v = (t < NCHUNK) ? cnt[b * NCHUNK + t] : 0;
    int incl;
    int excl = block_excl_scan<8>(v, t, &incl);
    if (t < NCHUNK) cnt[b * NCHUNK + t] = excl;
    if (t == NCHUNK - 1) btot[b] = incl;
}

// ---------------- Pass C: partition edges; bbase computed in-block ----------------
__global__ __launch_bounds__(256) void k_part(const int* __restrict__ rows,
                                              const int* __restrict__ cols,
                                              const int* __restrict__ cnt,
                                              const int* __restrict__ btot,
                                              int* __restrict__ bbase_out,
                                              int* __restrict__ ebuf) {
    __shared__ int bb[NB + 1];
    __shared__ int cur[NB];
    __shared__ int S0s;
    int ch = blockIdx.x, t = threadIdx.x;
    int incl;
    int v0 = btot[t];
    int e0 = block_excl_scan<4>(v0, t, &incl);
    bb[t] = e0;
    if (t == 255) S0s = incl;
    __syncthreads();
    int t2 = t + 256;
    int v1 = (t2 < NB) ? btot[t2] : 0;
    int e1 = block_excl_scan<4>(v1, t, &incl);
    if (t2 <= NB) bb[t2] = e1 + S0s;
    __syncthreads();
    for (int b = t; b < NB; b += 256) cur[b] = bb[b] + cnt[b * NCHUNK + ch];
    if (ch == 0)
        for (int i = t; i <= NB; i += 256) bbase_out[i] = bb[i];
    __syncthreads();
    for (int e = ch * EPB + t; e < (ch + 1) * EPB; e += 256) {
        int c = cols[e], r = rows[e];
        int pos = atomicAdd(&cur[c >> 7], 1);
        ebuf[pos] = (r << 7) | (c & 127);
    }
}

// ---------------- Pass D: bucket counting sort -> srows(ushort)/off/dinv + x->fp16 ----------------
__global__ __launch_bounds__(256) void k_bsort(const int* __restrict__ ebuf,
                                               const int* __restrict__ bbase,
                                               const float* __restrict__ x,
                                               int* __restrict__ off,
                                               float* __restrict__ dinv,
                                               ushort_t* __restrict__ srows,
                                               __half* __restrict__ xs) {
    __shared__ int   ldeg[128];
    __shared__ int   lcur[128];
    __shared__ float ldinv[128];
    int b = blockIdx.x, t = threadIdx.x;
    int n0 = b << 7;
    int nloc = min(128, NN - n0);
    int beg = bbase[b], end = bbase[b + 1];
    if (t < 128) ldeg[t] = 0;
    __syncthreads();
    for (int i = beg + t; i < end; i += 256)
        atomicAdd(&ldeg[ebuf[i] & 127], 1);
    __syncthreads();
    int v = (t < nloc) ? ldeg[t] : 0;
    int incl;
    int excl = block_excl_scan<4>(v, t, &incl);
    if (t < nloc) {
        off[n0 + t]  = beg + excl + v;            // END offset convention
        float d = rsqrtf((float)(v + 1));         // +1 self-loop
        dinv[n0 + t] = d;
        ldinv[t] = d;
        lcur[t] = beg + excl;
    }
    __syncthreads();
    for (int i = beg + t; i < end; i += 256) {
        int e = ebuf[i];
        int pos = atomicAdd(&lcur[e & 127], 1);
        srows[pos] = (ushort_t)(e >> 7);
    }
    // fused: xs[row] = fp16(dinv[row] * x[row]) for this bucket's rows
    const float4* Xx = (const float4*)x;
#pragma unroll
    for (int i = 0; i < 8; ++i) {
        int f4 = t + i * 256;                     // 0..2047 (128 rows x 16 f4)
        int rloc = f4 >> 4, kq = f4 & 15;
        if (rloc < nloc) {
            float d = ldinv[rloc];
            float4 vv = Xx[(size_t)(n0 + rloc) * 16 + kq];
            __half2 h[2];
            h[0] = __floats2half2_rn(d * vv.x, d * vv.y);
            h[1] = __floats2half2_rn(d * vv.z, d * vv.w);
            ((float2*)xs)[(size_t)(n0 + rloc) * 16 + kq] = *(float2*)h;
        }
    }
}

// ---------------- gather on pre-scaled fp16 rows, fp16 output ----------------
// SRC' (fp16) scaled by dinv[row]; DST[c] = fp16(dinv[c]*(sum_e SRC'[r] + SRC'[c])).
// ZB: first 512 blocks also zero zbuf[131072] (gsum).
template<int FEAT, bool ZB>
__global__ __launch_bounds__(256) void k_gath_h(const int* __restrict__ off,
                                                const ushort_t* __restrict__ srows,
                                                const float* __restrict__ dinv,
                                                const __half* __restrict__ SRC,
                                                __half* __restrict__ DST,
                                                float* __restrict__ zbuf) {
    if (ZB) {
        if (blockIdx.x < 512) zbuf[(blockIdx.x << 8) + threadIdx.x] = 0.f;
    }
    constexpr int NC = FEAT / 8;    // 16B chunks (8 halfs) per row
    constexpr int PL = NC / 8;      // chunks per lane (1 for 64, 2 for 128)
    int node = blockIdx.x * 4 + (threadIdx.x >> 6);
    int lane = threadIdx.x & 63;
    int slot = lane >> 3, q = lane & 7;
    if (node >= NN) return;
    int beg = node ? off[node - 1] : 0;
    int end = off[node];
    float di = dinv[node];
    const float4* S4 = (const float4*)SRC;

    float acc[PL][8];
#pragma unroll
    for (int i = 0; i < PL; ++i)
#pragma unroll
        for (int j = 0; j < 8; ++j) acc[i][j] = 0.f;

    if (slot == 0) {
#pragma unroll
        for (int i = 0; i < PL; ++i) {
            float4 raw = S4[node * NC + i * 8 + q];
            const __half2* h = (const __half2*)&raw;
#pragma unroll
            for (int j = 0; j < 4; ++j) {
                float2 f = __half22float2(h[j]);
                acc[i][2 * j + 0] = f.x;
                acc[i][2 * j + 1] = f.y;
            }
        }
    }
    for (int e = beg + slot; e < end; e += 8) {
        int r = srows[e];
#pragma unroll
        for (int i = 0; i < PL; ++i) {
            float4 raw = S4[r * NC + i * 8 + q];
            const __half2* h = (const __half2*)&raw;
#pragma unroll
            for (int j = 0; j < 4; ++j) {
                float2 f = __half22float2(h[j]);
                acc[i][2 * j + 0] += f.x;
                acc[i][2 * j + 1] += f.y;
            }
        }
    }
#pragma unroll
    for (int d = 8; d < 64; d <<= 1)
#pragma unroll
        for (int i = 0; i < PL; ++i)
#pragma unroll
            for (int j = 0; j < 8; ++j)
                acc[i][j] += __shfl_xor(acc[i][j], d, 64);

    if (lane < 8) {
        float4* D4 = (float4*)DST;   // 8 halfs per float4
#pragma unroll
        for (int i = 0; i < PL; ++i) {
            float4 pk;
            __half2* hp = (__half2*)&pk;
            hp[0] = __floats2half2_rn(di * acc[i][0], di * acc[i][1]);
            hp[1] = __floats2half2_rn(di * acc[i][2], di * acc[i][3]);
            hp[2] = __floats2half2_rn(di * acc[i][4], di * acc[i][5]);
            hp[3] = __floats2half2_rn(di * acc[i][6], di * acc[i][7]);
            D4[node * NC + i * 8 + lane] = pk;
        }
    }
}

// ---------------- MFMA node GEMM: Y[M,128] = X[M,K](fp16) @ W + bias, relu ----------------
template<int K, bool RS, bool POOL>
__global__ __launch_bounds__(256) void gemm_mf(const __half* __restrict__ X,
                                               const __half* __restrict__ WT,
                                               const float* __restrict__ bias,
                                               const float* __restrict__ rs,
                                               const int* __restrict__ batch,
                                               float* __restrict__ Y, int M) {
    constexpr int KP = K + 8;                 // padded fp16 row stride (16B-aligned)
    __shared__ __half Xs[64 * KP];
    __shared__ __half Ws[128 * KP];
    __shared__ int sb[64];
    const int t = threadIdx.x;
    const int row0 = blockIdx.x * 64;

    const float4* X8 = (const float4*)X;
#pragma unroll
    for (int i = t; i < 64 * (K / 8); i += 256) {
        int r = i / (K / 8), ch = i % (K / 8);
        float4 v = make_float4(0.f, 0.f, 0.f, 0.f);
        if (row0 + r < M) v = X8[(size_t)(row0 + r) * (K / 8) + ch];
        *(float4*)&Xs[r * KP + ch * 8] = v;
    }
    const float4* W8 = (const float4*)WT;
#pragma unroll
    for (int i = t; i < 128 * (K / 8); i += 256) {
        int n = i / (K / 8), ch = i % (K / 8);
        *(float4*)&Ws[n * KP + ch * 8] = W8[i];
    }
    if (POOL) {
        if (t < 64) sb[t] = (row0 + t < M) ? batch[row0 + t] : -1;
    }
    __syncthreads();

    const int w  = t >> 6;
    const int l  = t & 63;
    const int lm = l & 15, lg = l >> 4;

    f32x4 acc[8];
#pragma unroll
    for (int c = 0; c < 8; ++c) acc[c] = (f32x4){0.f, 0.f, 0.f, 0.f};

#pragma unroll
    for (int kk = 0; kk < K / 32; ++kk) {
        f16x8 a = *(const f16x8*)&Xs[(16 * w + lm) * KP + kk * 32 + lg * 8];
#pragma unroll
        for (int c = 0; c < 8; ++c) {
            f16x8 bf = *(const f16x8*)&Ws[(16 * c + lm) * KP + kk * 32 + lg * 8];
            acc[c] = __builtin_amdgcn_mfma_f32_16x16x32_f16(a, bf, acc[c], 0, 0, 0);
        }
    }

    float bcol[8];
#pragma unroll
    for (int c = 0; c < 8; ++c) bcol[c] = bias[16 * c + lm];

    if (POOL) {
#pragma unroll
        for (int c = 0; c < 8; ++c) {
            int rung = -1;
            float run = 0.f;
#pragma unroll
            for (int j = 0; j < 4; ++j) {
                int rr = 16 * w + 4 * lg + j;
                int g = (row0 + rr < M) ? sb[rr] : -1;
                if (g != rung) {
                    if (rung >= 0) atomicAdd(&Y[rung * 128 + 16 * c + lm], run);
                    run = 0.f;
                    rung = g;
                }
                if (g >= 0) run += fmaxf(acc[c][j] + bcol[c], 0.f);
            }
            if (rung >= 0) atomicAdd(&Y[rung * 128 + 16 * c + lm], run);
        }
        return;
    }

    __half* Yh = (__half*)Y;
#pragma unroll
    for (int j = 0; j < 4; ++j) {
        int r = row0 + 16 * w + 4 * lg + j;
        if (r < M) {
            float d = RS ? rs[r] : 1.f;
#pragma unroll
            for (int c = 0; c < 8; ++c) {
                float v = d * fmaxf(acc[c][j] + bcol[c], 0.f);
                Yh[(size_t)r * 128 + 16 * c + lm] = __float2half(v);
            }
        }
    }
}

// ---------------- MFMA batched GEMM: {A,B}arr[c][g][t] = mean(GE) @ W1-half (fp16 out) ----------------
__global__ __launch_bounds__(256) void gemm_bat(const float* __restrict__ gsum,
                                                const float* __restrict__ inv,
                                                const __half* __restrict__ Whl,
                                                __half* __restrict__ Aarr,
                                                __half* __restrict__ Barr) {
    constexpr int KP = 128 + 8;
    __shared__ __half Xs[64 * KP];
    __shared__ __half Ws[128 * KP];
    const int t = threadIdx.x;
    const int row0 = blockIdx.x * 64;
    const int y = blockIdx.y, z = blockIdx.z;

    const float4* G4 = (const float4*)gsum;
#pragma unroll
    for (int i = t; i < 64 * 16; i += 256) {
        int r = i >> 4, ch = i & 15;
        int g = row0 + r;
        float iv = inv[g];
        float4 a = G4[g * 32 + ch * 2];
        float4 b4 = G4[g * 32 + ch * 2 + 1];
        float4 pk;
        __half2* hp = (__half2*)&pk;
        hp[0] = __floats2half2_rn(iv * a.x, iv * a.y);
        hp[1] = __floats2half2_rn(iv * a.z, iv * a.w);
        hp[2] = __floats2half2_rn(iv * b4.x, iv * b4.y);
        hp[3] = __floats2half2_rn(iv * b4.z, iv * b4.w);
        *(float4*)&Xs[r * KP + ch * 8] = pk;
    }

    const int w  = t >> 6;
    const int l  = t & 63;
    const int lm = l & 15, lg = l >> 4;

    f32x4 acc[8];
#pragma unroll
    for (int c = 0; c < 8; ++c) acc[c] = (f32x4){0.f, 0.f, 0.f, 0.f};

    const float4* W8 = (const float4*)Whl;
#pragma unroll
    for (int pass = 0; pass < 2; ++pass) {
        __syncthreads();   // Xs ready (pass 0) / Ws no longer read (pass 1)
        size_t wbase = ((size_t)pass * 32 + z) * 256 * 16;  // f16x8 units
#pragma unroll
        for (int i = t; i < 128 * 16; i += 256) {
            int n = i >> 4, ch = i & 15;
            *(float4*)&Ws[n * KP + ch * 8] = W8[wbase + (size_t)(y * 128 + n) * 16 + ch];
        }
        __syncthreads();
#pragma unroll
        for (int kk = 0; kk < 4; ++kk) {
            f16x8 a = *(const f16x8*)&Xs[(16 * w + lm) * KP + kk * 32 + lg * 8];
#pragma unroll
            for (int c = 0; c < 8; ++c) {
                f16x8 bf = *(const f16x8*)&Ws[(16 * c + lm) * KP + kk * 32 + lg * 8];
                acc[c] = __builtin_amdgcn_mfma_f32_16x16x32_f16(a, bf, acc[c], 0, 0, 0);
            }
        }
    }

    __half* Obase = (z & 1) ? Barr : Aarr;
#pragma unroll
    for (int j = 0; j < 4; ++j) {
        int g = row0 + 16 * w + 4 * lg + j;
        size_t rb = ((size_t)(z >> 1) * NG + g) * HID + y * 128;
#pragma unroll
        for (int c = 0; c < 8; ++c)
            Obase[rb + 16 * c + lm] = __float2half(acc[c][j]);
    }
}

// ---------------- pair epilogue (fp16 A/B tables) ----------------
__global__ __launch_bounds__(256) void k_pair(const __half* __restrict__ Aarr,
                                              const __half* __restrict__ Barr,
                                              const int* __restrict__ ddb,
                                              const int* __restrict__ ecl,
                                              const float* __restrict__ B1,
                                              const float* __restrict__ W2,
                                              const float* __restrict__ B2,
                                              float* __restrict__ out) {
    int p = blockIdx.x * 4 + (threadIdx.x >> 6);
    int lane = threadIdx.x & 63;
    int c = ecl[p];
    int a = ddb[p];
    int b = ddb[NP + p];
    const float2* rA = (const float2*)&Aarr[((size_t)c * NG + a) * HID];  // 4 halfs
    const float2* rB = (const float2*)&Barr[((size_t)c * NG + b) * HID];
    const float4* b1 = (const float4*)&B1[c * HID];
    const float4* w2 = (const float4*)&W2[c * HID];
    float2 rawa = rA[lane], rawb = rB[lane];
    const __half2* ha = (const __half2*)&rawa;
    const __half2* hb = (const __half2*)&rawb;
    float4 v1 = b1[lane], v2 = w2[lane];
    float2 a01 = __half22float2(ha[0]), a23 = __half22float2(ha[1]);
    float2 b01 = __half22float2(hb[0]), b23 = __half22float2(hb[1]);
    float hx = a01.x + b01.x + v1.x;
    float hy = a01.y + b01.y + v1.y;
    float hz = a23.x + b23.x + v1.z;
    float hw = a23.y + b23.y + v1.w;
    float s = 0.f;
    s = fmaf(hx > 0.f ? hx : 0.f, v2.x, s);
    s = fmaf(hy > 0.f ? hy : 0.f, v2.y, s);
    s = fmaf(hz > 0.f ? hz : 0.f, v2.z, s);
    s = fmaf(hw > 0.f ? hw : 0.f, v2.w, s);
    for (int o = 32; o; o >>= 1) s += __shfl_down(s, o, 64);
    if (lane == 0) out[p] = s + B2[c];
}

// ---------------- launch ----------------
extern "C" void kernel_launch(void* const* d_in, const int* in_sizes, int n_in,
                              void* d_out, int out_size, void* d_ws, size_t ws_size,
                              hipStream_t stream) {
    const float* x    = (const float*)d_in[0];
    const float* c1w  = (const float*)d_in[1];
    const float* c1b  = (const float*)d_in[2];
    const float* c2w  = (const float*)d_in[3];
    const float* c2b  = (const float*)d_in[4];
    const float* rw1  = (const float*)d_in[5];
    const float* rb1  = (const float*)d_in[6];
    const float* rw2  = (const float*)d_in[7];
    const float* rb2  = (const float*)d_in[8];
    const int*   eidx = (const int*)d_in[9];    // [2, NE]: rows then cols
    const int*   batch= (const int*)d_in[10];
    const int*   ddb  = (const int*)d_in[11];   // [2, NP]
    const int*   ecl  = (const int*)d_in[12];
    float* out = (float*)d_out;

    // ---- workspace layout (floats) ----
    // off(50048) | srows(NE ints; used as NE ushorts) | dinv(50048) | bufA(6.4M) | bufB(6.4M)
    int*   off   = (int*)d_ws;
    int*   srows = off + 50048;
    float* dinv  = (float*)(srows + NE);
    float* bufA  = dinv + 50048;
    float* bufB  = bufA + NN * EMB;

    int*      ebuf  = (int*)bufA;
    int*      cnt   = (int*)(bufB + 1700000);
    int*      btot  = cnt + NB * NCHUNK;
    int*      bbase = btot + 512;
    __half*   xs    = (__half*)bufB;
    __half*   aggXh = (__half*)bufA;
    __half*   H1h   = (__half*)bufB;
    __half*   aggHh = (__half*)bufA;
    float*    gsum  = bufA + 4500000;
    __half*   w1t   = (__half*)(bufA + 4700000);
    __half*   w2t   = (__half*)(bufA + 4710000);
    float*    inv   = bufA + 4730000;
    __half*   Whl   = (__half*)(bufB + 4300000);
    __half*   Aarr  = (__half*)bufA;
    __half*   Barr  = (__half*)bufB;
    ushort_t* srowsU = (ushort_t*)srows;

    const int* erow = eidx;
    const int* ecol = eidx + NE;

    // ---- fused prep: edge histogram + weight fp16 tables + graph inv-counts ----
    k_prep0<<<1012, 256, 0, stream>>>(ecol, c1w, c2w, rw1, batch,
                                      cnt, w1t, w2t, Whl, inv);

    // ---- CSR build ----
    k_bscan<<<NB,  512, 0, stream>>>(cnt, btot);
    k_part <<<NCHUNK, 256, 0, stream>>>(erow, ecol, cnt, btot, bbase, ebuf);
    k_bsort<<<NB,  256, 0, stream>>>(ebuf, bbase, x, off, dinv, srowsU, xs);

    // ---- layer 1: aggX(fp16) = gather(xs) [+ zero gsum] ; H1'(fp16) = dinv*relu(aggX@W1+b1) ----
    k_gath_h<INCH,true><<<CDIV(NN,4),256,0,stream>>>(off, srowsU, dinv, xs, aggXh, gsum);
    gemm_mf<INCH,true,false><<<CDIV(NN,64),256,0,stream>>>(aggXh, w1t, c1b, dinv, nullptr, (float*)H1h, NN);

    // ---- layer 2: aggH(fp16) = gather(H1') ; MFMA gemm2 + fused mean-pool atomics ----
    k_gath_h<EMB,false><<<CDIV(NN,4),256,0,stream>>>(off, srowsU, dinv, H1h, aggHh, nullptr);
    gemm_mf<EMB,false,true><<<CDIV(NN,64),256,0,stream>>>(aggHh, w2t, c2b, nullptr, batch, gsum, NN);

    // ---- regressor: MFMA {A,B} fp16 tables (hi+lo compensated, mean folded), pair epilogue ----
    dim3 bgrid(NG/64, 2, 2*NCL);
    gemm_bat<<<bgrid,256,0,stream>>>(gsum, inv, Whl, Aarr, Barr);
    k_pair<<<NP/4,256,0,stream>>>(Aarr, Barr, ddb, ecl, rb1, rw2, rb2, out);
}